// Round 5
// baseline (182.980 us; speedup 1.0000x reference)
//
#include <hip/hip_runtime.h>
#include <stdint.h>

#define N_COLS 8192
#define N_ROWS 8192
#define C4 (N_COLS / 4)
#define FP8_MAX_F 448.0f
#define EPS_F 1e-12f
#define ROWCHUNKS 256
#define ROWS_PER_BLOCK (N_ROWS / ROWCHUNKS)   // 32
#define QBLOCKS 2048

typedef float floatx4 __attribute__((ext_vector_type(4)));   // native vec for nt-store

// ---------------------------------------------------------------------------
// Pass 1: per-(rowchunk, column) partial abs-max. No atomics, no init needed.
// grid (8, 256) = 2048 blocks -> 8 blocks/CU -> 8 waves/SIMD (full TLP for
// a pure-load kernel). Each thread: 4 columns x 32 rows.
// ---------------------------------------------------------------------------
__global__ __launch_bounds__(256) void col_amax_partial(const float4* __restrict__ x4,
                                                        float4* __restrict__ partial4) {
    int c4 = blockIdx.x * 256 + threadIdx.x;
    const float4* p = x4 + (size_t)blockIdx.y * ROWS_PER_BLOCK * C4 + c4;
    uint32_t m0 = 0, m1 = 0, m2 = 0, m3 = 0;   // |x| bit-pattern max == float max
#pragma unroll 8
    for (int r = 0; r < ROWS_PER_BLOCK; ++r) {
        float4 v = p[(size_t)r * C4];
        m0 = max(m0, __float_as_uint(v.x) & 0x7FFFFFFFu);
        m1 = max(m1, __float_as_uint(v.y) & 0x7FFFFFFFu);
        m2 = max(m2, __float_as_uint(v.z) & 0x7FFFFFFFu);
        m3 = max(m3, __float_as_uint(v.w) & 0x7FFFFFFFu);
    }
    float4 o;
    o.x = __uint_as_float(m0);
    o.y = __uint_as_float(m1);
    o.z = __uint_as_float(m2);
    o.w = __uint_as_float(m3);
    partial4[(size_t)blockIdx.y * C4 + c4] = o;
}

// ---------------------------------------------------------------------------
// Pass 2: reduce 256 partials per column; emit bit-exact forward scale
// (IEEE 448/amax, matches numpy) and the dequant inverse (amax/448).
// 8 MB read, L2-resident, ~3 us.
// ---------------------------------------------------------------------------
__global__ __launch_bounds__(256) void scale_from_partials(const float* __restrict__ partial,
                                                           float* __restrict__ scale,
                                                           float* __restrict__ inv) {
    int c = blockIdx.x * 256 + threadIdx.x;
    float a = 0.0f;
#pragma unroll 8
    for (int k = 0; k < ROWCHUNKS; ++k)
        a = fmaxf(a, partial[(size_t)k * N_COLS + c]);
    a = fmaxf(a, EPS_F);
    scale[c] = FP8_MAX_F / a;   // IEEE divide: must be bit-identical to numpy
    inv[c]   = a / FP8_MAX_F;   // dequant multiplier (1-2 ulp vs q/scale: fine)
}

// ---------------------------------------------------------------------------
// Pass 3: scale -> clip -> HW e4m3fn RNE cast -> dequant-multiply.
// T is a multiple of C4, so each thread's column index ci = gtid & (C4-1) is
// loop-invariant: hoist the scale/inv loads. 2-way unroll for vmem ILP;
// loads batched ahead of stores. Non-temporal stores (out is write-once).
// ---------------------------------------------------------------------------
static __device__ __forceinline__ floatx4 fq4(float4 v, float4 s, float4 w) {
    float a0 = fminf(fmaxf(v.x * s.x, -FP8_MAX_F), FP8_MAX_F);
    float a1 = fminf(fmaxf(v.y * s.y, -FP8_MAX_F), FP8_MAX_F);
    float a2 = fminf(fmaxf(v.z * s.z, -FP8_MAX_F), FP8_MAX_F);
    float a3 = fminf(fmaxf(v.w * s.w, -FP8_MAX_F), FP8_MAX_F);
    int p = __builtin_amdgcn_cvt_pk_fp8_f32(a0, a1, 0, false);
    p = __builtin_amdgcn_cvt_pk_fp8_f32(a2, a3, p, true);
    floatx4 o;
    o.x = __builtin_amdgcn_cvt_f32_fp8(p, 0) * w.x;
    o.y = __builtin_amdgcn_cvt_f32_fp8(p, 1) * w.y;
    o.z = __builtin_amdgcn_cvt_f32_fp8(p, 2) * w.z;
    o.w = __builtin_amdgcn_cvt_f32_fp8(p, 3) * w.w;
    return o;
}

__global__ __launch_bounds__(256) void quant_kernel(const float4* __restrict__ x4,
                                                    const float4* __restrict__ scale4,
                                                    const float4* __restrict__ inv4,
                                                    floatx4* __restrict__ out4) {
    const size_t n4 = (size_t)N_ROWS * C4;
    const size_t T = (size_t)QBLOCKS * 256;          // 524288; T % C4 == 0
    const int NCHUNK = (int)(n4 / T);                // 32
    size_t gtid = (size_t)blockIdx.x * 256 + threadIdx.x;
    int ci = (int)(gtid & (size_t)(C4 - 1));
    float4 s = scale4[ci];                           // loop-invariant
    float4 w = inv4[ci];
    for (int c = 0; c < NCHUNK; c += 2) {
        size_t i0 = (size_t)c * T + gtid;
        size_t i1 = i0 + T;
        float4 v0 = x4[i0];
        float4 v1 = x4[i1];
        floatx4 o0 = fq4(v0, s, w);
        floatx4 o1 = fq4(v1, s, w);
        __builtin_nontemporal_store(o0, &out4[i0]);
        __builtin_nontemporal_store(o1, &out4[i1]);
    }
}

extern "C" void kernel_launch(void* const* d_in, const int* in_sizes, int n_in,
                              void* d_out, int out_size, void* d_ws, size_t ws_size,
                              hipStream_t stream) {
    const float* x = (const float*)d_in[0];
    float* out = (float*)d_out;
    // ws: partial (256*8192 f32 = 8 MB) | scale (32 KB) | inv (32 KB)
    float* partial = (float*)d_ws;
    float* scale = (float*)((char*)d_ws + (size_t)ROWCHUNKS * N_COLS * sizeof(float));
    float* inv = scale + N_COLS;

    dim3 g1(N_COLS / 1024, ROWCHUNKS);
    col_amax_partial<<<g1, 256, 0, stream>>>((const float4*)x, (float4*)partial);

    scale_from_partials<<<N_COLS / 256, 256, 0, stream>>>(partial, scale, inv);

    quant_kernel<<<QBLOCKS, 256, 0, stream>>>((const float4*)x, (const float4*)scale,
                                              (const float4*)inv, (floatx4*)out);
}

// Round 6
// 155.050 us; speedup vs baseline: 1.1801x; 1.1801x over previous
//
#include <hip/hip_runtime.h>
#include <stdint.h>

#define N_COLS 8192
#define N_ROWS 8192
#define C4 (N_COLS / 4)
#define FP8_MAX_F 448.0f
#define EPS_F 1e-12f
#define ROWCHUNKS 128
#define ROWS_PER_BLOCK (N_ROWS / ROWCHUNKS)   // 64
#define QBLOCKS 2048

typedef float floatx4 __attribute__((ext_vector_type(4)));   // native vec for nt ld/st

// ---------------------------------------------------------------------------
// Pass 1: per-(rowchunk, column) partial abs-max. No atomics, no init needed.
// grid (8, 128) x 256 threads; each thread owns 4 columns x 64 rows.
// (Exact round-4 structure — known 149 us total.)
// ---------------------------------------------------------------------------
__global__ __launch_bounds__(256) void col_amax_partial(const float4* __restrict__ x4,
                                                        float4* __restrict__ partial4) {
    int c4 = blockIdx.x * 256 + threadIdx.x;
    const float4* p = x4 + (size_t)blockIdx.y * ROWS_PER_BLOCK * C4 + c4;
    uint32_t m0 = 0, m1 = 0, m2 = 0, m3 = 0;   // |x| bit-pattern max == float max
#pragma unroll 8
    for (int r = 0; r < ROWS_PER_BLOCK; ++r) {
        float4 v = p[(size_t)r * C4];
        m0 = max(m0, __float_as_uint(v.x) & 0x7FFFFFFFu);
        m1 = max(m1, __float_as_uint(v.y) & 0x7FFFFFFFu);
        m2 = max(m2, __float_as_uint(v.z) & 0x7FFFFFFFu);
        m3 = max(m3, __float_as_uint(v.w) & 0x7FFFFFFFu);
    }
    float4 o;
    o.x = __uint_as_float(m0);
    o.y = __uint_as_float(m1);
    o.z = __uint_as_float(m2);
    o.w = __uint_as_float(m3);
    partial4[(size_t)blockIdx.y * C4 + c4] = o;
}

// ---------------------------------------------------------------------------
// Pass 2: reduce 128 partials per column; emit bit-exact forward scale
// (IEEE 448/amax, matches numpy) and the dequant inverse (amax/448).
// ---------------------------------------------------------------------------
__global__ __launch_bounds__(256) void scale_from_partials(const float* __restrict__ partial,
                                                           float* __restrict__ scale,
                                                           float* __restrict__ inv) {
    int c = blockIdx.x * 256 + threadIdx.x;
    float a = 0.0f;
#pragma unroll 8
    for (int k = 0; k < ROWCHUNKS; ++k)
        a = fmaxf(a, partial[(size_t)k * N_COLS + c]);
    a = fmaxf(a, EPS_F);
    scale[c] = FP8_MAX_F / a;   // IEEE divide: must be bit-identical to numpy
    inv[c]   = a / FP8_MAX_F;   // dequant multiplier (1-2 ulp vs q/scale: fine)
}

// ---------------------------------------------------------------------------
// Pass 3: scale -> clip -> HW e4m3fn RNE cast -> dequant-multiply.
// ONE change vs round 4: x is read with NON-TEMPORAL loads (use-once data,
// don't allocate in L2/L3 -> leave cache capacity to the store stream).
// Stores stay non-temporal. Reverse chunk order kept (round-4 known-good).
// ---------------------------------------------------------------------------
__global__ __launch_bounds__(256) void quant_kernel(const floatx4* __restrict__ x4,
                                                    const float4* __restrict__ scale4,
                                                    const float4* __restrict__ inv4,
                                                    floatx4* __restrict__ out4) {
    const size_t n4 = (size_t)N_ROWS * C4;
    const size_t T = (size_t)QBLOCKS * 256;          // threads in grid
    const int NCHUNK = (int)(n4 / T);                // 32
    size_t gtid = (size_t)blockIdx.x * 256 + threadIdx.x;
    for (int c = NCHUNK - 1; c >= 0; --c) {
        size_t i = (size_t)c * T + gtid;
        size_t ci = i & (size_t)(C4 - 1);
        float4 s = scale4[ci];
        float4 w = inv4[ci];
        floatx4 v = __builtin_nontemporal_load(&x4[i]);
        float a0 = fminf(fmaxf(v.x * s.x, -FP8_MAX_F), FP8_MAX_F);
        float a1 = fminf(fmaxf(v.y * s.y, -FP8_MAX_F), FP8_MAX_F);
        float a2 = fminf(fmaxf(v.z * s.z, -FP8_MAX_F), FP8_MAX_F);
        float a3 = fminf(fmaxf(v.w * s.w, -FP8_MAX_F), FP8_MAX_F);
        int p = __builtin_amdgcn_cvt_pk_fp8_f32(a0, a1, 0, false);
        p = __builtin_amdgcn_cvt_pk_fp8_f32(a2, a3, p, true);
        floatx4 o;
        o.x = __builtin_amdgcn_cvt_f32_fp8(p, 0) * w.x;
        o.y = __builtin_amdgcn_cvt_f32_fp8(p, 1) * w.y;
        o.z = __builtin_amdgcn_cvt_f32_fp8(p, 2) * w.z;
        o.w = __builtin_amdgcn_cvt_f32_fp8(p, 3) * w.w;
        __builtin_nontemporal_store(o, &out4[i]);
    }
}

extern "C" void kernel_launch(void* const* d_in, const int* in_sizes, int n_in,
                              void* d_out, int out_size, void* d_ws, size_t ws_size,
                              hipStream_t stream) {
    const float* x = (const float*)d_in[0];
    float* out = (float*)d_out;
    // ws: partial (128*8192 f32 = 4 MB) | scale (32 KB) | inv (32 KB)
    float* partial = (float*)d_ws;
    float* scale = (float*)((char*)d_ws + (size_t)ROWCHUNKS * N_COLS * sizeof(float));
    float* inv = scale + N_COLS;

    dim3 g1(N_COLS / 1024, ROWCHUNKS);
    col_amax_partial<<<g1, 256, 0, stream>>>((const float4*)x, (float4*)partial);

    scale_from_partials<<<N_COLS / 256, 256, 0, stream>>>(partial, scale, inv);

    quant_kernel<<<QBLOCKS, 256, 0, stream>>>((const floatx4*)x, (const float4*)scale,
                                              (const float4*)inv, (floatx4*)out);
}